// Round 1
// baseline (181.441 us; speedup 1.0000x reference)
//
#include <hip/hip_runtime.h>

// Problem: x [B=128, C=3, L=256, L=256] fp32; X/Y/W/H [N=4, B=128] int32
// box bounds. Output: x with pixels inside any box zeroed (broadcast over C).
//
// Memory-bound: 100.7 MB read + 100.7 MB write. Roofline at ~6.5 TB/s
// (demonstrated by the harness's own fill dispatches) = ~31 us.
//
// Key change vs previous version: all box-parameter loads are now provably
// block-uniform (b derived from blockIdx.x only) -> compiler emits s_load
// scalar loads instead of 16 per-thread vector loads. Previous version spent
// ~1/3 of its L1 request bandwidth broadcasting box params.

constexpr int BB = 128;
constexpr int CC = 3;
constexpr int LL = 256;
constexpr int NN = 4;

// Block = 512 consecutive float4 (2 per thread) = 8 full rows of one (b,c)
// plane. 32 blocks per plane. Each wave covers one full 256-col row per
// float4, so row predicates are wave-uniform.
__global__ __launch_bounds__(256) void mask_square_kernel(
    const float4* __restrict__ x,
    const int* __restrict__ Xb,
    const int* __restrict__ Yb,
    const int* __restrict__ Wb,
    const int* __restrict__ Hb,
    float4* __restrict__ out)
{
    const int blk  = blockIdx.x;
    const int bc   = blk >> 5;              // plane index = b*CC + c (uniform)
    const int b    = bc / CC;               // scalar magic-mul divide (uniform)
    const int row0 = (blk & 31) << 3;       // first of this block's 8 rows
    const int tid  = threadIdx.x;
    const int base = blk * 512 + tid;

    const int col0 = (tid & 63) << 2;       // first col of this thread's group
    const int ra   = row0 + (tid >> 6);     // row of first float4 (wave-uniform)
    const int rb   = ra + 4;                // row of second float4

    float4 va = x[base];
    float4 vb = x[base + 256];

    int ma0 = 0, ma1 = 0, ma2 = 0, ma3 = 0;
    int mb0 = 0, mb1 = 0, mb2 = 0, mb3 = 0;
#pragma unroll
    for (int n = 0; n < NN; ++n) {
        // Uniform indices -> s_load_dword through the scalar cache.
        const int Xn = Xb[n * BB + b];
        const int Yn = Yb[n * BB + b];
        const int Wn = Wb[n * BB + b];
        const int Hn = Hb[n * BB + b];

        // col in [X, X+W]  <=>  (unsigned)(col - X) <= W   (W,H in [0,64))
        const int dc  = col0 - Xn;
        const int ina = (unsigned)(ra - Yn) <= (unsigned)Hn;  // wave-uniform
        const int inb = (unsigned)(rb - Yn) <= (unsigned)Hn;  // wave-uniform
        const int c0  = (unsigned)(dc    ) <= (unsigned)Wn;
        const int c1  = (unsigned)(dc + 1) <= (unsigned)Wn;
        const int c2  = (unsigned)(dc + 2) <= (unsigned)Wn;
        const int c3  = (unsigned)(dc + 3) <= (unsigned)Wn;

        ma0 |= ina & c0;  ma1 |= ina & c1;  ma2 |= ina & c2;  ma3 |= ina & c3;
        mb0 |= inb & c0;  mb1 |= inb & c1;  mb2 |= inb & c2;  mb3 |= inb & c3;
    }

    if (ma0) va.x = 0.0f;
    if (ma1) va.y = 0.0f;
    if (ma2) va.z = 0.0f;
    if (ma3) va.w = 0.0f;
    if (mb0) vb.x = 0.0f;
    if (mb1) vb.y = 0.0f;
    if (mb2) vb.z = 0.0f;
    if (mb3) vb.w = 0.0f;

    out[base]       = va;
    out[base + 256] = vb;
}

extern "C" void kernel_launch(void* const* d_in, const int* in_sizes, int n_in,
                              void* d_out, int out_size, void* d_ws, size_t ws_size,
                              hipStream_t stream) {
    const float4* x  = (const float4*)d_in[0];
    const int*    Xb = (const int*)d_in[1];
    const int*    Yb = (const int*)d_in[2];
    const int*    Wb = (const int*)d_in[3];
    const int*    Hb = (const int*)d_in[4];
    float4*       o  = (float4*)d_out;

    const int total4 = BB * CC * LL * LL / 4;   // 6,291,456 float4
    const int blocks = total4 / 512;            // 12,288 blocks
    mask_square_kernel<<<blocks, 256, 0, stream>>>(x, Xb, Yb, Wb, Hb, o);
}

// Round 3
// 172.807 us; speedup vs baseline: 1.0500x; 1.0500x over previous
//
#include <hip/hip_runtime.h>

// Problem: x [B=128, C=3, L=256, L=256] fp32; X/Y/W/H [N=4, B=128] int32
// box bounds. Output: x with pixels inside any box zeroed (broadcast over C).
//
// Pure streaming: 100.7 MB read + 100.7 MB write, zero reuse. Target is the
// m13 float4-copy ceiling (~6.3 TB/s -> ~32 us).
//
// Structure: 8 float4 per thread, all loads issued before any dependent use
// (128 B/lane in flight), mask math overlapped with load returns, then 8
// stores. Nontemporal hints (no byte reused -> don't allocate cache).
// Native clang vector type (ext_vector_type) because the nontemporal
// builtins reject HIP_vector_type.

constexpr int BB = 128;
constexpr int CC = 3;
constexpr int LL = 256;
constexpr int NN = 4;
constexpr int U  = 8;     // float4 per thread

typedef float f32x4 __attribute__((ext_vector_type(4)));

// Block = 2048 consecutive float4 = 32 rows of one (b,c) plane.
// 8 blocks per plane, 3072 blocks total. Wave covers full 256-col rows,
// so all row predicates are wave-uniform.
__global__ __launch_bounds__(256) void mask_square_kernel(
    const f32x4* __restrict__ x,
    const int* __restrict__ Xb,
    const int* __restrict__ Yb,
    const int* __restrict__ Wb,
    const int* __restrict__ Hb,
    f32x4* __restrict__ out)
{
    const int blk  = blockIdx.x;
    const int bc   = blk >> 3;              // plane index b*CC + c (uniform)
    const int b    = bc / CC;               // uniform -> scalar magic-mul
    const int row0 = (blk & 7) << 5;        // first of this block's 32 rows
    const int tid  = threadIdx.x;
    const int base = blk * 2048 + tid;

    const int col0 = (tid & 63) << 2;       // first col of this thread's group
    const int r0   = row0 + (tid >> 6);     // row of u=0 float4 (wave-uniform)

    // Issue all 8 loads up front (independent, 128 B/lane outstanding).
    f32x4 v0 = __builtin_nontemporal_load(&x[base + 256 * 0]);
    f32x4 v1 = __builtin_nontemporal_load(&x[base + 256 * 1]);
    f32x4 v2 = __builtin_nontemporal_load(&x[base + 256 * 2]);
    f32x4 v3 = __builtin_nontemporal_load(&x[base + 256 * 3]);
    f32x4 v4 = __builtin_nontemporal_load(&x[base + 256 * 4]);
    f32x4 v5 = __builtin_nontemporal_load(&x[base + 256 * 5]);
    f32x4 v6 = __builtin_nontemporal_load(&x[base + 256 * 6]);
    f32x4 v7 = __builtin_nontemporal_load(&x[base + 256 * 7]);

    // m[u]: bit j set -> component j of float4 u is inside some box.
    int m[U];
#pragma unroll
    for (int u = 0; u < U; ++u) m[u] = 0;

#pragma unroll
    for (int n = 0; n < NN; ++n) {
        // Uniform indices -> s_load through the scalar cache.
        const int Xn = Xb[n * BB + b];
        const int Yn = Yb[n * BB + b];
        const int Wn = Wb[n * BB + b];
        const int Hn = Hb[n * BB + b];

        // col in [X, X+W] <=> (unsigned)(col - X) <= W   (W,H in [0,64))
        const int dc = col0 - Xn;
        const int colbits =
            ((unsigned)(dc    ) <= (unsigned)Wn ? 1 : 0) |
            ((unsigned)(dc + 1) <= (unsigned)Wn ? 2 : 0) |
            ((unsigned)(dc + 2) <= (unsigned)Wn ? 4 : 0) |
            ((unsigned)(dc + 3) <= (unsigned)Wn ? 8 : 0);

#pragma unroll
        for (int u = 0; u < U; ++u) {
            // row of float4 u = r0 + 4*u (wave-uniform predicate)
            const int rin = (unsigned)(r0 + 4 * u - Yn) <= (unsigned)Hn;
            m[u] |= rin ? colbits : 0;
        }
    }

#define APPLY_STORE(u, vv)                                          \
    {                                                               \
        f32x4 w = vv;                                               \
        if (m[u] & 1) w.x = 0.0f;                                   \
        if (m[u] & 2) w.y = 0.0f;                                   \
        if (m[u] & 4) w.z = 0.0f;                                   \
        if (m[u] & 8) w.w = 0.0f;                                   \
        __builtin_nontemporal_store(w, &out[base + 256 * (u)]);     \
    }

    APPLY_STORE(0, v0)
    APPLY_STORE(1, v1)
    APPLY_STORE(2, v2)
    APPLY_STORE(3, v3)
    APPLY_STORE(4, v4)
    APPLY_STORE(5, v5)
    APPLY_STORE(6, v6)
    APPLY_STORE(7, v7)
#undef APPLY_STORE
}

extern "C" void kernel_launch(void* const* d_in, const int* in_sizes, int n_in,
                              void* d_out, int out_size, void* d_ws, size_t ws_size,
                              hipStream_t stream) {
    const f32x4* x  = (const f32x4*)d_in[0];
    const int*   Xb = (const int*)d_in[1];
    const int*   Yb = (const int*)d_in[2];
    const int*   Wb = (const int*)d_in[3];
    const int*   Hb = (const int*)d_in[4];
    f32x4*       o  = (f32x4*)d_out;

    const int total4 = BB * CC * LL * LL / 4;       // 6,291,456 float4
    const int blocks = total4 / (256 * U);          // 3,072 blocks
    mask_square_kernel<<<blocks, 256, 0, stream>>>(x, Xb, Yb, Wb, Hb, o);
}